// Round 9
// baseline (89.022 us; speedup 1.0000x reference)
//
#include <hip/hip_runtime.h>

#define BB 8
#define LL 2048
#define DD 512
#define NN 64
#define TT 64
#define CC 32   // LL/TT chunks

typedef __attribute__((ext_vector_type(8))) short bf16x8;
typedef __attribute__((ext_vector_type(4))) float f32x4;

__device__ __forceinline__ float2 cmul(float2 a, float2 b) {
  return make_float2(a.x*b.x - a.y*b.y, a.x*b.y + a.y*b.x);
}
__device__ __forceinline__ unsigned f2b(float f) {   // f32 -> bf16 (RNE)
  union { float f; unsigned u; } v; v.f = f;
  return (v.u + 0x7FFFu + ((v.u >> 16) & 1u)) >> 16;
}
__device__ __forceinline__ float b2f(unsigned h) {
  union { unsigned u; float f; } v; v.u = h << 16; return v.f;
}

// ---------------------------------------------------------------------------
// K0: transpose u[b][l][d] f32 -> ut[b][d][l] f32. 64x64 tiles, full coverage.
// ---------------------------------------------------------------------------
__global__ __launch_bounds__(256) void k0_tr(
    const float* __restrict__ u, float* __restrict__ ut) {
  int bid = blockIdx.x;
  int dt8 = bid & 7, lt = (bid >> 3) & 31, b = bid >> 8;
  int l0 = lt * 64, d0 = dt8 * 64;
  int tid = threadIdx.x;
  __shared__ float tl[64][65];         // [l][d]
  #pragma unroll
  for (int it = 0; it < 2; ++it) {
    int row = it * 32 + (tid >> 3), seg = tid & 7;   // row = l
    const float* src = &u[((size_t)(b*LL + l0 + row))*DD + d0 + seg*8];
    float4 v0 = *(const float4*)src;
    float4 v1 = *(const float4*)(src + 4);
    tl[row][seg*8+0]=v0.x; tl[row][seg*8+1]=v0.y;
    tl[row][seg*8+2]=v0.z; tl[row][seg*8+3]=v0.w;
    tl[row][seg*8+4]=v1.x; tl[row][seg*8+5]=v1.y;
    tl[row][seg*8+6]=v1.z; tl[row][seg*8+7]=v1.w;
  }
  __syncthreads();
  #pragma unroll
  for (int it = 0; it < 2; ++it) {
    int row = it * 32 + (tid >> 3), seg = tid & 7;   // row = d
    float o[8];
    #pragma unroll
    for (int j = 0; j < 8; ++j) o[j] = tl[seg*8 + j][row];
    float* dst = &ut[((size_t)(b*DD + d0 + row))*LL + l0 + seg*8];
    *(float4*)dst = *(float4*)&o[0];
    *(float4*)(dst + 4) = *(float4*)&o[4];
  }
}

// ---------------------------------------------------------------------------
// K1: per-d setup. PRE-SWIZZLED bf16 MFMA B-operand tables:
//  W2s[d]: row n2, k s; W[s]=Abar^(63-s)*Bbar (re/im rows).         (B phase)
//  G2s[d]: row r, k n2; G[r]=C*Abar^(r+1) (re / -im cols).          (D phase)
//  Th/Tl[d]: row r, k s; Tlow[r][s]=K[r-s] (s<=r else 0), hi+lo split.
//  P[d][n] = Abar^64 (f32 scan propagator).
// ---------------------------------------------------------------------------
__global__ __launch_bounds__(64) void k1_setup(
    const float* __restrict__ A_re, const float* __restrict__ A_im,
    const float* __restrict__ C_re, const float* __restrict__ C_im,
    const float* __restrict__ log_dt,
    ushort* __restrict__ W2s, ushort* __restrict__ G2s,
    ushort* __restrict__ Th2s, ushort* __restrict__ Tl2s,
    float2* __restrict__ P) {
  int d = blockIdx.x, n = threadIdx.x;
  int idx = d * NN + n;
  __shared__ ushort Wl[8192], Gl[8192], Thl[4096], Tll[4096];
  __shared__ float Kl[64];
  float dt  = expf(log_dt[d]);
  float dre = dt * A_re[idx], dim = dt * A_im[idx];
  float er  = expf(dre);
  float abr = er * cosf(dim), abi = er * sinf(dim);
  const float eps = 1e-8f;
  float nre = abr - 1.0f + eps, nim = abi;
  float qre = dre + eps,        qim = dim;
  float inv = 1.0f / (qre*qre + qim*qim);
  float bbr = dt * (nre*qre + nim*qim) * inv;
  float bbi = dt * (nim*qre - nre*qim) * inv;
  float2 a  = make_float2(abr, abi);
  float2 bb = make_float2(bbr, bbi);
  float2 cc = make_float2(C_re[idx], C_im[idx]);

  // W frags
  {
    float2 w = bb;
    for (int s = TT - 1; s >= 0; --s) {
      int ks = s >> 5, lk = (s >> 3) & 3, e = s & 7;
      {
        int n2 = 2*n; int nh = n2>>6, t = (n2>>4)&3, lr = n2&15, l = lk*16+lr;
        Wl[(((nh*4+t)*2+ks)*64 + l)*8 + e] = (ushort)f2b(w.x);
      }
      {
        int n2 = 2*n+1; int nh = n2>>6, t = (n2>>4)&3, lr = n2&15, l = lk*16+lr;
        Wl[(((nh*4+t)*2+ks)*64 + l)*8 + e] = (ushort)f2b(w.y);
      }
      w = cmul(w, a);
    }
  }
  // G frags
  {
    float2 g = cmul(cc, a);
    for (int r = 0; r < TT; ++r) {
      int rh = r >> 5, t = (r >> 4) & 1, lr = r & 15;
      {
        int n2 = 2*n; int ks = n2>>5, lk = (n2>>3)&3, e = n2&7, l = lk*16+lr;
        Gl[(((rh*2+t)*4+ks)*64 + l)*8 + e] = (ushort)f2b(g.x);
      }
      {
        int n2 = 2*n+1; int ks = n2>>5, lk = (n2>>3)&3, e = n2&7, l = lk*16+lr;
        Gl[(((rh*2+t)*4+ks)*64 + l)*8 + e] = (ushort)f2b(-g.y);
      }
      g = cmul(g, a);
    }
  }
  // P = a^64
  {
    float2 p = a;
    #pragma unroll
    for (int q = 0; q < 6; ++q) p = cmul(p, p);
    P[idx] = p;
  }
  // K[m] = Re(sum_n C*Abar^m*Bbar) -> LDS
  {
    float tre = cc.x*bb.x - cc.y*bb.y;
    float tim = cc.x*bb.y + cc.y*bb.x;
    for (int m = 0; m < TT; ++m) {
      float v = tre;
      #pragma unroll
      for (int off = 32; off > 0; off >>= 1) v += __shfl_down(v, off, 64);
      if (n == 0) Kl[m] = v;
      float t2 = tre*abr - tim*abi;
      tim = tre*abi + tim*abr;
      tre = t2;
    }
  }
  __syncthreads();
  // Toeplitz frags (hi+lo): row r = rh*32+t*16+(n&15), k s = ks*32+(n>>4)*8+e
  {
    #pragma unroll
    for (int rh = 0; rh < 2; ++rh)
      #pragma unroll
      for (int t = 0; t < 2; ++t)
        #pragma unroll
        for (int ks = 0; ks < 2; ++ks) {
          int r = rh*32 + t*16 + (n & 15);
          #pragma unroll
          for (int e = 0; e < 8; ++e) {
            int s = ks*32 + (n >> 4)*8 + e;
            float val = (s <= r) ? Kl[r - s] : 0.f;
            unsigned hv = f2b(val);
            int o = rh*2048 + ((t*2+ks)*64 + n)*8 + e;
            Thl[o] = (ushort)hv;
            Tll[o] = (ushort)f2b(val - b2f(hv));
          }
        }
  }
  __syncthreads();
  // coalesced copy-out
  {
    uint4* Wg = (uint4*)(W2s + (size_t)d * 8192);
    uint4* Gg = (uint4*)(G2s + (size_t)d * 8192);
    uint4* Thg = (uint4*)(Th2s + (size_t)d * 4096);
    uint4* Tlg = (uint4*)(Tl2s + (size_t)d * 4096);
    for (int i = n; i < 1024; i += 64) {
      Wg[i] = ((const uint4*)Wl)[i];
      Gg[i] = ((const uint4*)Gl)[i];
    }
    for (int i = n; i < 512; i += 64) {
      Thg[i] = ((const uint4*)Thl)[i];
      Tlg[i] = ((const uint4*)Tll)[i];
    }
  }
}

// ---------------------------------------------------------------------------
// K2 MFMA: Z-GEMM + split-precision Toeplitz conv + Kogge-Stone scan +
// cross-GEMM; writes full output column yt[b][d][:] in f32 (coalesced).
// Block (256 thr) per (b,d); XCD x hosts d in [x*64,x*64+64) (tables L2-hot).
//  u staged f32 -> bf16 hi+lo LDS tiles (rows c+1; row 0 = zeros).
//  B: Z[c][n2] = sum_s u_hi[c][s]*W[s][n2]        (8 MFMA/wave) -> Sf
//  T: acc2 = Th*u_hi + Th*u_lo + Tl*u_hi          (12 MFMA/wave)
//  scan: Kogge-Stone, 5 steps, f32                 -> Zs (bf16 S_excl)
//  D: acc2 += sum_n2 S[c][n2]*G[n2][r]            (8 MFMA/wave)
//  out: acc2 -> ylds f32 (alias of u tiles) -> yt linear 8KB
// ---------------------------------------------------------------------------
__global__ __launch_bounds__(256, 4) void k2_mfma(
    const float* __restrict__ ut, const ushort* __restrict__ W2s,
    const ushort* __restrict__ G2s, const ushort* __restrict__ Th2s,
    const ushort* __restrict__ Tl2s, const float2* __restrict__ P,
    float* __restrict__ yt) {
  int bid = blockIdx.x;
  int x = bid & 7;                     // XCD
  int d = x * 64 + ((bid >> 3) & 63);  // d-contiguous per XCD
  int b = bid >> 9;
  int tid = threadIdx.x;
  int l = tid & 63, wv = tid >> 6;
  int lr = l & 15, lk = l >> 4;
  int m0 = (wv & 1) * 16;              // c-half
  int half = wv >> 1;                  // n-half (B) / r-half (T,D)

  __shared__ __align__(16) char smem[8448 + 8448 + 17160];
  char*  u_hi = smem;                  // [33][128] bf16, rows c+1, swizzled
  char*  u_lo = smem + 4224;
  char*  Zs   = smem + 8448;           // [33][256] bf16
  float* Sf   = (float*)(smem + 16896);// [33][130] f32
  char*  ylds = smem;                  // alias (8192B), dead u tiles

  // --- stage u f32 -> hi/lo bf16 (coalesced 8KB load)
  {
    const float* up = &ut[((size_t)(b * DD + d)) * LL + tid * 8];
    float4 v0 = *(const float4*)up;
    float4 v1 = *(const float4*)(up + 4);
    float f[8] = {v0.x,v0.y,v0.z,v0.w,v1.x,v1.y,v1.z,v1.w};
    unsigned h[8], lo[8];
    #pragma unroll
    for (int j = 0; j < 8; ++j) {
      h[j]  = f2b(f[j]);
      lo[j] = f2b(f[j] - b2f(h[j]));
    }
    uint4 ph = make_uint4(h[0]|(h[1]<<16), h[2]|(h[3]<<16),
                          h[4]|(h[5]<<16), h[6]|(h[7]<<16));
    uint4 pl = make_uint4(lo[0]|(lo[1]<<16), lo[2]|(lo[3]<<16),
                          lo[4]|(lo[5]<<16), lo[6]|(lo[7]<<16));
    int row = (tid >> 3) + 1;
    int off = row*128 + (((tid & 7) * 16) ^ ((row & 7) << 4));
    *(uint4*)(u_hi + off) = ph;
    *(uint4*)(u_lo + off) = pl;
  }
  if (tid < 8) {
    *(uint4*)(u_hi + tid * 16) = make_uint4(0,0,0,0);
    *(uint4*)(u_lo + tid * 16) = make_uint4(0,0,0,0);
  }
  for (int i = tid; i < 130; i += 256) Sf[i] = 0.f;   // Sf row 0 = zeros
  __syncthreads();

  // --- B: Z-GEMM (u_hi) -> Sf rows c+1
  {
    const ushort* Wd = W2s + (size_t)d * 8192 + (size_t)half * 4096;
    f32x4 acc[4] = {{0,0,0,0},{0,0,0,0},{0,0,0,0},{0,0,0,0}};
    #pragma unroll
    for (int ks = 0; ks < 2; ++ks) {
      int arow = m0 + lr + 1;
      bf16x8 af = *(const bf16x8*)(u_hi + arow*128 +
                     ((ks*64 + lk*16) ^ ((arow & 7) << 4)));
      #pragma unroll
      for (int t = 0; t < 4; ++t) {
        bf16x8 bfr = *(const bf16x8*)(Wd + ((t*2 + ks)*64 + l)*8);
        acc[t] = __builtin_amdgcn_mfma_f32_16x16x32_bf16(af, bfr, acc[t], 0,0,0);
      }
    }
    #pragma unroll
    for (int t = 0; t < 4; ++t)
      #pragma unroll
      for (int j = 0; j < 4; ++j) {
        int c  = m0 + lk*4 + j;
        int n2 = half*64 + t*16 + lr;
        int col = (n2 >> 1) + (n2 & 1) * 64;
        Sf[(c + 1) * 130 + col] = acc[t][j];
      }
  }

  // --- T: split-precision local conv GEMM into acc2
  f32x4 acc2[2] = {{0,0,0,0},{0,0,0,0}};
  {
    const ushort* Tdh = Th2s + (size_t)d * 4096 + (size_t)half * 2048;
    const ushort* Tdl = Tl2s + (size_t)d * 4096 + (size_t)half * 2048;
    #pragma unroll
    for (int ks = 0; ks < 2; ++ks) {
      int arow = m0 + lr + 1;
      int aoff = (ks*64 + lk*16) ^ ((arow & 7) << 4);
      bf16x8 ah = *(const bf16x8*)(u_hi + arow*128 + aoff);
      bf16x8 al = *(const bf16x8*)(u_lo + arow*128 + aoff);
      #pragma unroll
      for (int t = 0; t < 2; ++t) {
        bf16x8 bh = *(const bf16x8*)(Tdh + ((t*2 + ks)*64 + l)*8);
        bf16x8 bl = *(const bf16x8*)(Tdl + ((t*2 + ks)*64 + l)*8);
        acc2[t] = __builtin_amdgcn_mfma_f32_16x16x32_bf16(ah, bh, acc2[t], 0,0,0);
        acc2[t] = __builtin_amdgcn_mfma_f32_16x16x32_bf16(al, bh, acc2[t], 0,0,0);
        acc2[t] = __builtin_amdgcn_mfma_f32_16x16x32_bf16(ah, bl, acc2[t], 0,0,0);
      }
    }
  }
  __syncthreads();

  // --- Kogge-Stone scan rows 1..32: Sf[r] += p^(2^k)*Sf[r-2^k]
  {
    int n = tid & 63;
    int rb = 1 + (tid >> 6);
    float2 p = P[(size_t)d * NN + n];
    float vre[8], vim[8];
    #pragma unroll
    for (int q = 0; q < 8; ++q) {
      int r = rb + 4*q;
      vre[q] = Sf[r*130 + n];
      vim[q] = Sf[r*130 + 64 + n];
    }
    #pragma unroll
    for (int k = 0; k < 5; ++k) {
      int s = 1 << k;
      float pre[8], pim[8];
      #pragma unroll
      for (int q = 0; q < 8; ++q) {
        int pr = rb + 4*q - s; if (pr < 0) pr = 0;
        pre[q] = Sf[pr*130 + n];
        pim[q] = Sf[pr*130 + 64 + n];
      }
      __syncthreads();
      #pragma unroll
      for (int q = 0; q < 8; ++q) {
        vre[q] = fmaf(p.x, pre[q], fmaf(-p.y, pim[q], vre[q]));
        vim[q] = fmaf(p.x, pim[q], fmaf( p.y, pre[q], vim[q]));
        Sf[(rb + 4*q)*130 + n]      = vre[q];
        Sf[(rb + 4*q)*130 + 64 + n] = vim[q];
      }
      float npx = p.x*p.x - p.y*p.y;
      p.y = 2.f * p.x * p.y; p.x = npx;
      __syncthreads();
    }
    #pragma unroll
    for (int q = 0; q < 8; ++q) {
      int r = rb + 4*q;                        // Zs row r = S before chunk r
      unsigned pk = f2b(vre[q]) | (f2b(vim[q]) << 16);
      *(unsigned*)(Zs + r*256 + ((4*n) ^ ((r & 7) << 4))) = pk;
    }
    if (tid < 64) *(unsigned*)(Zs + 4*tid) = 0u; // row 0 = zeros
  }
  __syncthreads();

  // --- D: cross GEMM accumulating into acc2
  {
    const ushort* Gd = G2s + (size_t)d * 8192 + (size_t)half * 4096;
    #pragma unroll
    for (int ks = 0; ks < 4; ++ks) {
      int arow = m0 + lr;
      bf16x8 af = *(const bf16x8*)(Zs + arow*256 +
                     ((ks*64 + lk*16) ^ ((arow & 7) << 4)));
      #pragma unroll
      for (int t = 0; t < 2; ++t) {
        bf16x8 bfr = *(const bf16x8*)(Gd + ((t*4 + ks)*64 + l)*8);
        acc2[t] = __builtin_amdgcn_mfma_f32_16x16x32_bf16(af, bfr, acc2[t], 0,0,0);
      }
    }
  }
  // --- out: acc2 -> ylds f32 [c][r] -> yt linear 8KB
  #pragma unroll
  for (int t = 0; t < 2; ++t)
    #pragma unroll
    for (int j = 0; j < 4; ++j) {
      int c = m0 + lk*4 + j;
      int r = half*32 + t*16 + lr;
      *(float*)(ylds + (c*64 + r)*4) = acc2[t][j];
    }
  __syncthreads();
  {
    float4 o0 = *(const float4*)(ylds + tid * 32);
    float4 o1 = *(const float4*)(ylds + tid * 32 + 16);
    float* dst = &yt[((size_t)(b * DD + d)) * LL + tid * 8];
    *(float4*)dst = o0;
    *(float4*)(dst + 4) = o1;
  }
}

// ---------------------------------------------------------------------------
// K4: transpose yt[b][d][l] f32 -> y[b][l][d] f32. Full 64x64 coverage.
// ---------------------------------------------------------------------------
__global__ __launch_bounds__(256) void k4_tr(
    const float* __restrict__ yt, float* __restrict__ y) {
  int bid = blockIdx.x;
  int dt8 = bid & 7, lt = (bid >> 3) & 31, b = bid >> 8;
  int l0 = lt * 64, d0 = dt8 * 64;
  int tid = threadIdx.x;
  __shared__ float tl[64][65];         // [d][l]
  #pragma unroll
  for (int it = 0; it < 2; ++it) {
    int row = it * 32 + (tid >> 3), seg = tid & 7;   // row = d
    const float* src = &yt[((size_t)(b*DD + d0 + row))*LL + l0 + seg*8];
    float4 v0 = *(const float4*)src;
    float4 v1 = *(const float4*)(src + 4);
    tl[row][seg*8+0]=v0.x; tl[row][seg*8+1]=v0.y;
    tl[row][seg*8+2]=v0.z; tl[row][seg*8+3]=v0.w;
    tl[row][seg*8+4]=v1.x; tl[row][seg*8+5]=v1.y;
    tl[row][seg*8+6]=v1.z; tl[row][seg*8+7]=v1.w;
  }
  __syncthreads();
  #pragma unroll
  for (int it = 0; it < 2; ++it) {
    int row = it * 32 + (tid >> 3), seg = tid & 7;   // row = l
    float o[8];
    #pragma unroll
    for (int j = 0; j < 8; ++j) o[j] = tl[seg*8 + j][row];
    float* dst = &y[((size_t)(b*LL + l0 + row))*DD + d0 + seg*8];
    *(float4*)dst = *(float4*)&o[0];
    *(float4*)(dst + 4) = *(float4*)&o[4];
  }
}

extern "C" void kernel_launch(void* const* d_in, const int* in_sizes, int n_in,
                              void* d_out, int out_size, void* d_ws, size_t ws_size,
                              hipStream_t stream) {
  const float* u      = (const float*)d_in[0];
  const float* A_re   = (const float*)d_in[1];
  const float* A_im   = (const float*)d_in[2];
  const float* C_re   = (const float*)d_in[3];
  const float* C_im   = (const float*)d_in[4];
  const float* log_dt = (const float*)d_in[5];
  float* y = (float*)d_out;

  // ws: yt f32 33.5MB | ut f32 33.5MB | W2s 8.4 | G2s 8.4 | Th 4.2 | Tl 4.2 | P
  float*  yt  = (float*)d_ws;
  float*  ut  = yt + (size_t)BB * DD * LL;
  ushort* W2s = (ushort*)(ut + (size_t)BB * DD * LL);
  ushort* G2s = W2s + (size_t)DD * 8192;
  ushort* Th  = G2s + (size_t)DD * 8192;
  ushort* Tl  = Th  + (size_t)DD * 4096;
  float2* P   = (float2*)(Tl + (size_t)DD * 4096);

  k0_tr   <<<BB * 32 * 8, 256, 0, stream>>>(u, ut);
  k1_setup<<<DD,          64,  0, stream>>>(A_re, A_im, C_re, C_im, log_dt,
                                            W2s, G2s, Th, Tl, P);
  k2_mfma <<<BB * DD,     256, 0, stream>>>(ut, W2s, G2s, Th, Tl, P, yt);
  k4_tr   <<<BB * 32 * 8, 256, 0, stream>>>(yt, y);
}

// Round 10
// 71.330 us; speedup vs baseline: 1.2480x; 1.2480x over previous
//
#include <hip/hip_runtime.h>

#define BB 8
#define LL 2048
#define DD 512
#define NN 64
#define TT 64
#define CC 32   // LL/TT chunks

typedef __attribute__((ext_vector_type(8))) short bf16x8;
typedef __attribute__((ext_vector_type(4))) float f32x4;

__device__ __forceinline__ float2 cmul(float2 a, float2 b) {
  return make_float2(a.x*b.x - a.y*b.y, a.x*b.y + a.y*b.x);
}
__device__ __forceinline__ unsigned f2b(float f) {   // f32 -> bf16 (RNE)
  union { float f; unsigned u; } v; v.f = f;
  return (v.u + 0x7FFFu + ((v.u >> 16) & 1u)) >> 16;
}
__device__ __forceinline__ float b2f(unsigned h) {
  union { unsigned u; float f; } v; v.u = h << 16; return v.f;
}

// ---------------------------------------------------------------------------
// K0: transpose u[b][l][d] f32 -> ut[b][d][l] f32. 64x64 tiles, full coverage.
// ---------------------------------------------------------------------------
__global__ __launch_bounds__(256) void k0_tr(
    const float* __restrict__ u, float* __restrict__ ut) {
  int bid = blockIdx.x;
  int dt8 = bid & 7, lt = (bid >> 3) & 31, b = bid >> 8;
  int l0 = lt * 64, d0 = dt8 * 64;
  int tid = threadIdx.x;
  __shared__ float tl[64][65];         // [l][d]
  #pragma unroll
  for (int it = 0; it < 2; ++it) {
    int row = it * 32 + (tid >> 3), seg = tid & 7;   // row = l
    const float* src = &u[((size_t)(b*LL + l0 + row))*DD + d0 + seg*8];
    float4 v0 = *(const float4*)src;
    float4 v1 = *(const float4*)(src + 4);
    tl[row][seg*8+0]=v0.x; tl[row][seg*8+1]=v0.y;
    tl[row][seg*8+2]=v0.z; tl[row][seg*8+3]=v0.w;
    tl[row][seg*8+4]=v1.x; tl[row][seg*8+5]=v1.y;
    tl[row][seg*8+6]=v1.z; tl[row][seg*8+7]=v1.w;
  }
  __syncthreads();
  #pragma unroll
  for (int it = 0; it < 2; ++it) {
    int row = it * 32 + (tid >> 3), seg = tid & 7;   // row = d
    float o[8];
    #pragma unroll
    for (int j = 0; j < 8; ++j) o[j] = tl[seg*8 + j][row];
    float* dst = &ut[((size_t)(b*DD + d0 + row))*LL + l0 + seg*8];
    *(float4*)dst = *(float4*)&o[0];
    *(float4*)(dst + 4) = *(float4*)&o[4];
  }
}

// ---------------------------------------------------------------------------
// K1: per-d setup, 256 threads/block (wave wv owns a 16-slice of s/r/m).
// Chains start via binary exponentiation (a16 = a^16); K[m] reduction is a
// 2-level LDS parallel reduction (no shfl chains). Emits pre-swizzled bf16
// MFMA B-operand tables W2s/G2s/Th/Tl + P (f32).
// ---------------------------------------------------------------------------
__global__ __launch_bounds__(256) void k1_setup(
    const float* __restrict__ A_re, const float* __restrict__ A_im,
    const float* __restrict__ C_re, const float* __restrict__ C_im,
    const float* __restrict__ log_dt,
    ushort* __restrict__ W2s, ushort* __restrict__ G2s,
    ushort* __restrict__ Th2s, ushort* __restrict__ Tl2s,
    float2* __restrict__ P) {
  int d = blockIdx.x;
  int tid = threadIdx.x;
  int n = tid & 63, wv = tid >> 6;
  int idx = d * NN + n;

  __shared__ ushort Wl[8192], Gl[8192];
  __shared__ __align__(16) char smU[16640];   // Kp f32[64][65] | later Th/Tl
  ushort* Thl = (ushort*)smU;                 // 8 KB
  ushort* Tll = (ushort*)(smU + 8192);        // 8 KB
  float*  Kp  = (float*)smU;                  // 16.6 KB (dies at Kq)
  __shared__ float Kq[64][5];
  __shared__ float Kl[64];

  float dt  = expf(log_dt[d]);
  float dre = dt * A_re[idx], dim = dt * A_im[idx];
  float er  = expf(dre);
  float abr = er * cosf(dim), abi = er * sinf(dim);
  const float eps = 1e-8f;
  float nre = abr - 1.0f + eps, nim = abi;
  float qre = dre + eps,        qim = dim;
  float inv = 1.0f / (qre*qre + qim*qim);
  float bbr = dt * (nre*qre + nim*qim) * inv;
  float bbi = dt * (nim*qre - nre*qim) * inv;
  float2 a  = make_float2(abr, abi);
  float2 bb = make_float2(bbr, bbi);
  float2 cc = make_float2(C_re[idx], C_im[idx]);

  // powers: a16, a32, a48; pw_wv = (a16)^wv
  float2 a2  = cmul(a, a),   a4  = cmul(a2, a2);
  float2 a8  = cmul(a4, a4), a16 = cmul(a8, a8);
  float2 a32 = cmul(a16, a16), a48 = cmul(a32, a16);
  float2 pw_wv = make_float2(1.f, 0.f);
  for (int q = 0; q < wv; ++q) pw_wv = cmul(pw_wv, a16);

  // P = a^64 (wave 0 only)
  if (wv == 0) P[idx] = cmul(a32, a32);

  // --- W slice: s in [wv*16, wv*16+15], descending; W[s] = bb*a^(63-s)
  {
    float2 sel = (wv == 0) ? a48 : (wv == 1) ? a32
               : (wv == 2) ? a16 : make_float2(1.f, 0.f);
    float2 w = cmul(bb, sel);          // W[s_top], s_top = wv*16+15
    for (int j = 15; j >= 0; --j) {
      int s = wv*16 + j;
      int ks = s >> 5, lk = (s >> 3) & 3, e = s & 7;
      {
        int n2 = 2*n; int nh = n2>>6, tq = (n2>>4)&3, lr = n2&15;
        Wl[(((nh*4+tq)*2+ks)*64 + lk*16+lr)*8 + e] = (ushort)f2b(w.x);
      }
      {
        int n2 = 2*n+1; int nh = n2>>6, tq = (n2>>4)&3, lr = n2&15;
        Wl[(((nh*4+tq)*2+ks)*64 + lk*16+lr)*8 + e] = (ushort)f2b(w.y);
      }
      w = cmul(w, a);
    }
  }
  // --- G slice: r in [wv*16, wv*16+15]; G[r] = cc*a^(r+1)
  {
    float2 g = cmul(cc, cmul(a, pw_wv));   // r = wv*16
    for (int j = 0; j < 16; ++j) {
      int r = wv*16 + j;
      int rh = r >> 5, tq = (r >> 4) & 1, lr = r & 15;
      {
        int n2 = 2*n; int ks = n2>>5, lk = (n2>>3)&3, e = n2&7;
        Gl[(((rh*2+tq)*4+ks)*64 + lk*16+lr)*8 + e] = (ushort)f2b(g.x);
      }
      {
        int n2 = 2*n+1; int ks = n2>>5, lk = (n2>>3)&3, e = n2&7;
        Gl[(((rh*2+tq)*4+ks)*64 + lk*16+lr)*8 + e] = (ushort)f2b(-g.y);
      }
      g = cmul(g, a);
    }
  }
  // --- K slice: Kp[m][n] = Re(cb * a^m), m in [wv*16, wv*16+15]
  {
    float2 cb = cmul(cc, bb);
    float2 t = cmul(cb, pw_wv);        // m = wv*16
    for (int j = 0; j < 16; ++j) {
      Kp[(wv*16 + j)*65 + n] = t.x;
      t = cmul(t, a);
    }
  }
  __syncthreads();
  // --- reduce K over n: 256 threads -> Kq[m][q] -> Kl[m]
  {
    int m = tid >> 2, q = tid & 3;
    float s = 0.f;
    #pragma unroll
    for (int j = 0; j < 16; ++j) s += Kp[m*65 + q*16 + j];
    Kq[m][q] = s;
  }
  __syncthreads();
  if (tid < 64) Kl[tid] = Kq[tid][0] + Kq[tid][1] + Kq[tid][2] + Kq[tid][3];
  __syncthreads();                     // Kl ready; Kp dead -> Th/Tl reuse smU

  // --- Toeplitz frags (hi+lo): wave wv = (t*2+ks); 16 elems/thread
  {
    int tq = wv >> 1, ks = wv & 1;
    #pragma unroll
    for (int rh = 0; rh < 2; ++rh) {
      int r = rh*32 + tq*16 + (n & 15);
      #pragma unroll
      for (int e = 0; e < 8; ++e) {
        int s = ks*32 + (n >> 4)*8 + e;
        float val = (s <= r) ? Kl[r - s] : 0.f;
        unsigned hv = f2b(val);
        int o = rh*2048 + (wv*64 + n)*8 + e;
        Thl[o] = (ushort)hv;
        Tll[o] = (ushort)f2b(val - b2f(hv));
      }
    }
  }
  __syncthreads();
  // --- coalesced copy-out
  {
    uint4* Wg  = (uint4*)(W2s  + (size_t)d * 8192);
    uint4* Gg  = (uint4*)(G2s  + (size_t)d * 8192);
    uint4* Thg = (uint4*)(Th2s + (size_t)d * 4096);
    uint4* Tlg = (uint4*)(Tl2s + (size_t)d * 4096);
    #pragma unroll
    for (int i = tid; i < 1024; i += 256) {
      Wg[i] = ((const uint4*)Wl)[i];
      Gg[i] = ((const uint4*)Gl)[i];
    }
    #pragma unroll
    for (int i = tid; i < 512; i += 256) {
      Thg[i] = ((const uint4*)Thl)[i];
      Tlg[i] = ((const uint4*)Tll)[i];
    }
  }
}

// ---------------------------------------------------------------------------
// K2 MFMA: Z-GEMM + split-precision Toeplitz conv + Kogge-Stone scan +
// cross-GEMM; writes full output column yt[b][d][:] in f32 (coalesced).
// Block (256 thr) per (b,d); XCD x hosts d in [x*64,x*64+64) (tables L2-hot).
// ---------------------------------------------------------------------------
__global__ __launch_bounds__(256, 4) void k2_mfma(
    const float* __restrict__ ut, const ushort* __restrict__ W2s,
    const ushort* __restrict__ G2s, const ushort* __restrict__ Th2s,
    const ushort* __restrict__ Tl2s, const float2* __restrict__ P,
    float* __restrict__ yt) {
  int bid = blockIdx.x;
  int x = bid & 7;                     // XCD
  int d = x * 64 + ((bid >> 3) & 63);  // d-contiguous per XCD
  int b = bid >> 9;
  int tid = threadIdx.x;
  int l = tid & 63, wv = tid >> 6;
  int lr = l & 15, lk = l >> 4;
  int m0 = (wv & 1) * 16;              // c-half
  int half = wv >> 1;                  // n-half (B) / r-half (T,D)

  __shared__ __align__(16) char smem[8448 + 8448 + 17160];
  char*  u_hi = smem;                  // [33][128] bf16, rows c+1, swizzled
  char*  u_lo = smem + 4224;
  char*  Zs   = smem + 8448;           // [33][256] bf16
  float* Sf   = (float*)(smem + 16896);// [33][130] f32
  char*  ylds = smem;                  // alias (8192B), dead u tiles

  // --- stage u f32 -> hi/lo bf16 (coalesced 8KB load)
  {
    const float* up = &ut[((size_t)(b * DD + d)) * LL + tid * 8];
    float4 v0 = *(const float4*)up;
    float4 v1 = *(const float4*)(up + 4);
    float f[8] = {v0.x,v0.y,v0.z,v0.w,v1.x,v1.y,v1.z,v1.w};
    unsigned h[8], lo[8];
    #pragma unroll
    for (int j = 0; j < 8; ++j) {
      h[j]  = f2b(f[j]);
      lo[j] = f2b(f[j] - b2f(h[j]));
    }
    uint4 ph = make_uint4(h[0]|(h[1]<<16), h[2]|(h[3]<<16),
                          h[4]|(h[5]<<16), h[6]|(h[7]<<16));
    uint4 pl = make_uint4(lo[0]|(lo[1]<<16), lo[2]|(lo[3]<<16),
                          lo[4]|(lo[5]<<16), lo[6]|(lo[7]<<16));
    int row = (tid >> 3) + 1;
    int off = row*128 + (((tid & 7) * 16) ^ ((row & 7) << 4));
    *(uint4*)(u_hi + off) = ph;
    *(uint4*)(u_lo + off) = pl;
  }
  if (tid < 8) {
    *(uint4*)(u_hi + tid * 16) = make_uint4(0,0,0,0);
    *(uint4*)(u_lo + tid * 16) = make_uint4(0,0,0,0);
  }
  for (int i = tid; i < 130; i += 256) Sf[i] = 0.f;   // Sf row 0 = zeros
  __syncthreads();

  // --- B: Z-GEMM (u_hi) -> Sf rows c+1
  {
    const ushort* Wd = W2s + (size_t)d * 8192 + (size_t)half * 4096;
    f32x4 acc[4] = {{0,0,0,0},{0,0,0,0},{0,0,0,0},{0,0,0,0}};
    #pragma unroll
    for (int ks = 0; ks < 2; ++ks) {
      int arow = m0 + lr + 1;
      bf16x8 af = *(const bf16x8*)(u_hi + arow*128 +
                     ((ks*64 + lk*16) ^ ((arow & 7) << 4)));
      #pragma unroll
      for (int t = 0; t < 4; ++t) {
        bf16x8 bfr = *(const bf16x8*)(Wd + ((t*2 + ks)*64 + l)*8);
        acc[t] = __builtin_amdgcn_mfma_f32_16x16x32_bf16(af, bfr, acc[t], 0,0,0);
      }
    }
    #pragma unroll
    for (int t = 0; t < 4; ++t)
      #pragma unroll
      for (int j = 0; j < 4; ++j) {
        int c  = m0 + lk*4 + j;
        int n2 = half*64 + t*16 + lr;
        int col = (n2 >> 1) + (n2 & 1) * 64;
        Sf[(c + 1) * 130 + col] = acc[t][j];
      }
  }

  // --- T: split-precision local conv GEMM into acc2
  f32x4 acc2[2] = {{0,0,0,0},{0,0,0,0}};
  {
    const ushort* Tdh = Th2s + (size_t)d * 4096 + (size_t)half * 2048;
    const ushort* Tdl = Tl2s + (size_t)d * 4096 + (size_t)half * 2048;
    #pragma unroll
    for (int ks = 0; ks < 2; ++ks) {
      int arow = m0 + lr + 1;
      int aoff = (ks*64 + lk*16) ^ ((arow & 7) << 4);
      bf16x8 ah = *(const bf16x8*)(u_hi + arow*128 + aoff);
      bf16x8 al = *(const bf16x8*)(u_lo + arow*128 + aoff);
      #pragma unroll
      for (int t = 0; t < 2; ++t) {
        bf16x8 bh = *(const bf16x8*)(Tdh + ((t*2 + ks)*64 + l)*8);
        bf16x8 bl = *(const bf16x8*)(Tdl + ((t*2 + ks)*64 + l)*8);
        acc2[t] = __builtin_amdgcn_mfma_f32_16x16x32_bf16(ah, bh, acc2[t], 0,0,0);
        acc2[t] = __builtin_amdgcn_mfma_f32_16x16x32_bf16(al, bh, acc2[t], 0,0,0);
        acc2[t] = __builtin_amdgcn_mfma_f32_16x16x32_bf16(ah, bl, acc2[t], 0,0,0);
      }
    }
  }
  __syncthreads();

  // --- Kogge-Stone scan rows 1..32: Sf[r] += p^(2^k)*Sf[r-2^k]
  {
    int n = tid & 63;
    int rb = 1 + (tid >> 6);
    float2 p = P[(size_t)d * NN + n];
    float vre[8], vim[8];
    #pragma unroll
    for (int q = 0; q < 8; ++q) {
      int r = rb + 4*q;
      vre[q] = Sf[r*130 + n];
      vim[q] = Sf[r*130 + 64 + n];
    }
    #pragma unroll
    for (int k = 0; k < 5; ++k) {
      int s = 1 << k;
      float pre[8], pim[8];
      #pragma unroll
      for (int q = 0; q < 8; ++q) {
        int pr = rb + 4*q - s; if (pr < 0) pr = 0;
        pre[q] = Sf[pr*130 + n];
        pim[q] = Sf[pr*130 + 64 + n];
      }
      __syncthreads();
      #pragma unroll
      for (int q = 0; q < 8; ++q) {
        vre[q] = fmaf(p.x, pre[q], fmaf(-p.y, pim[q], vre[q]));
        vim[q] = fmaf(p.x, pim[q], fmaf( p.y, pre[q], vim[q]));
        Sf[(rb + 4*q)*130 + n]      = vre[q];
        Sf[(rb + 4*q)*130 + 64 + n] = vim[q];
      }
      float npx = p.x*p.x - p.y*p.y;
      p.y = 2.f * p.x * p.y; p.x = npx;
      __syncthreads();
    }
    #pragma unroll
    for (int q = 0; q < 8; ++q) {
      int r = rb + 4*q;                        // Zs row r = S before chunk r
      unsigned pk = f2b(vre[q]) | (f2b(vim[q]) << 16);
      *(unsigned*)(Zs + r*256 + ((4*n) ^ ((r & 7) << 4))) = pk;
    }
    if (tid < 64) *(unsigned*)(Zs + 4*tid) = 0u; // row 0 = zeros
  }
  __syncthreads();

  // --- D: cross GEMM accumulating into acc2
  {
    const ushort* Gd = G2s + (size_t)d * 8192 + (size_t)half * 4096;
    #pragma unroll
    for (int ks = 0; ks < 4; ++ks) {
      int arow = m0 + lr;
      bf16x8 af = *(const bf16x8*)(Zs + arow*256 +
                     ((ks*64 + lk*16) ^ ((arow & 7) << 4)));
      #pragma unroll
      for (int t = 0; t < 2; ++t) {
        bf16x8 bfr = *(const bf16x8*)(Gd + ((t*4 + ks)*64 + l)*8);
        acc2[t] = __builtin_amdgcn_mfma_f32_16x16x32_bf16(af, bfr, acc2[t], 0,0,0);
      }
    }
  }
  // --- out: acc2 -> ylds f32 [c][r] -> yt linear 8KB
  #pragma unroll
  for (int t = 0; t < 2; ++t)
    #pragma unroll
    for (int j = 0; j < 4; ++j) {
      int c = m0 + lk*4 + j;
      int r = half*32 + t*16 + lr;
      *(float*)(ylds + (c*64 + r)*4) = acc2[t][j];
    }
  __syncthreads();
  {
    float4 o0 = *(const float4*)(ylds + tid * 32);
    float4 o1 = *(const float4*)(ylds + tid * 32 + 16);
    float* dst = &yt[((size_t)(b * DD + d)) * LL + tid * 8];
    *(float4*)dst = o0;
    *(float4*)(dst + 4) = o1;
  }
}

// ---------------------------------------------------------------------------
// K4: transpose yt[b][d][l] f32 -> y[b][l][d] f32. Full 64x64 coverage.
// ---------------------------------------------------------------------------
__global__ __launch_bounds__(256) void k4_tr(
    const float* __restrict__ yt, float* __restrict__ y) {
  int bid = blockIdx.x;
  int dt8 = bid & 7, lt = (bid >> 3) & 31, b = bid >> 8;
  int l0 = lt * 64, d0 = dt8 * 64;
  int tid = threadIdx.x;
  __shared__ float tl[64][65];         // [d][l]
  #pragma unroll
  for (int it = 0; it < 2; ++it) {
    int row = it * 32 + (tid >> 3), seg = tid & 7;   // row = d
    const float* src = &yt[((size_t)(b*DD + d0 + row))*LL + l0 + seg*8];
    float4 v0 = *(const float4*)src;
    float4 v1 = *(const float4*)(src + 4);
    tl[row][seg*8+0]=v0.x; tl[row][seg*8+1]=v0.y;
    tl[row][seg*8+2]=v0.z; tl[row][seg*8+3]=v0.w;
    tl[row][seg*8+4]=v1.x; tl[row][seg*8+5]=v1.y;
    tl[row][seg*8+6]=v1.z; tl[row][seg*8+7]=v1.w;
  }
  __syncthreads();
  #pragma unroll
  for (int it = 0; it < 2; ++it) {
    int row = it * 32 + (tid >> 3), seg = tid & 7;   // row = l
    float o[8];
    #pragma unroll
    for (int j = 0; j < 8; ++j) o[j] = tl[seg*8 + j][row];
    float* dst = &y[((size_t)(b*LL + l0 + row))*DD + d0 + seg*8];
    *(float4*)dst = *(float4*)&o[0];
    *(float4*)(dst + 4) = *(float4*)&o[4];
  }
}

extern "C" void kernel_launch(void* const* d_in, const int* in_sizes, int n_in,
                              void* d_out, int out_size, void* d_ws, size_t ws_size,
                              hipStream_t stream) {
  const float* u      = (const float*)d_in[0];
  const float* A_re   = (const float*)d_in[1];
  const float* A_im   = (const float*)d_in[2];
  const float* C_re   = (const float*)d_in[3];
  const float* C_im   = (const float*)d_in[4];
  const float* log_dt = (const float*)d_in[5];
  float* y = (float*)d_out;

  // ws: yt f32 33.5MB | ut f32 33.5MB | W2s 8.4 | G2s 8.4 | Th 4.2 | Tl 4.2 | P
  float*  yt  = (float*)d_ws;
  float*  ut  = yt + (size_t)BB * DD * LL;
  ushort* W2s = (ushort*)(ut + (size_t)BB * DD * LL);
  ushort* G2s = W2s + (size_t)DD * 8192;
  ushort* Th  = G2s + (size_t)DD * 8192;
  ushort* Tl  = Th  + (size_t)DD * 4096;
  float2* P   = (float2*)(Tl + (size_t)DD * 4096);

  k0_tr   <<<BB * 32 * 8, 256, 0, stream>>>(u, ut);
  k1_setup<<<DD,          256, 0, stream>>>(A_re, A_im, C_re, C_im, log_dt,
                                            W2s, G2s, Th, Tl, P);
  k2_mfma <<<BB * DD,     256, 0, stream>>>(ut, W2s, G2s, Th, Tl, P, yt);
  k4_tr   <<<BB * 32 * 8, 256, 0, stream>>>(yt, y);
}

// Round 11
// 65.802 us; speedup vs baseline: 1.3529x; 1.0840x over previous
//
#include <hip/hip_runtime.h>

#define BB 8
#define LL 2048
#define DD 512
#define NN 64
#define TT 64
#define CC 32   // LL/TT chunks

typedef __attribute__((ext_vector_type(8))) short bf16x8;
typedef __attribute__((ext_vector_type(4))) float f32x4;

__device__ __forceinline__ float2 cmul(float2 a, float2 b) {
  return make_float2(a.x*b.x - a.y*b.y, a.x*b.y + a.y*b.x);
}
__device__ __forceinline__ unsigned f2b(float f) {   // f32 -> bf16 (RNE)
  union { float f; unsigned u; } v; v.f = f;
  return (v.u + 0x7FFFu + ((v.u >> 16) & 1u)) >> 16;
}
__device__ __forceinline__ float b2f(unsigned h) {
  union { unsigned u; float f; } v; v.u = h << 16; return v.f;
}

// ---------------------------------------------------------------------------
// K0: transpose u[b][l][d] f32 -> ut_hi/ut_lo[b][d][l] bf16 (hi + residual).
// Moves the hi/lo split VALU into this memory-bound kernel.
// ---------------------------------------------------------------------------
__global__ __launch_bounds__(256) void k0_tr(
    const float* __restrict__ u, ushort* __restrict__ uth,
    ushort* __restrict__ utl) {
  int bid = blockIdx.x;
  int dt8 = bid & 7, lt = (bid >> 3) & 31, b = bid >> 8;
  int l0 = lt * 64, d0 = dt8 * 64;
  int tid = threadIdx.x;
  __shared__ float tl[64][65];         // [l][d]
  #pragma unroll
  for (int it = 0; it < 2; ++it) {
    int row = it * 32 + (tid >> 3), seg = tid & 7;   // row = l
    const float* src = &u[((size_t)(b*LL + l0 + row))*DD + d0 + seg*8];
    float4 v0 = *(const float4*)src;
    float4 v1 = *(const float4*)(src + 4);
    tl[row][seg*8+0]=v0.x; tl[row][seg*8+1]=v0.y;
    tl[row][seg*8+2]=v0.z; tl[row][seg*8+3]=v0.w;
    tl[row][seg*8+4]=v1.x; tl[row][seg*8+5]=v1.y;
    tl[row][seg*8+6]=v1.z; tl[row][seg*8+7]=v1.w;
  }
  __syncthreads();
  #pragma unroll
  for (int it = 0; it < 2; ++it) {
    int row = it * 32 + (tid >> 3), seg = tid & 7;   // row = d
    unsigned h[8], lo[8];
    #pragma unroll
    for (int j = 0; j < 8; ++j) {
      float f = tl[seg*8 + j][row];
      h[j]  = f2b(f);
      lo[j] = f2b(f - b2f(h[j]));
    }
    uint4 ph = make_uint4(h[0]|(h[1]<<16), h[2]|(h[3]<<16),
                          h[4]|(h[5]<<16), h[6]|(h[7]<<16));
    uint4 pl = make_uint4(lo[0]|(lo[1]<<16), lo[2]|(lo[3]<<16),
                          lo[4]|(lo[5]<<16), lo[6]|(lo[7]<<16));
    size_t off = ((size_t)(b*DD + d0 + row))*LL + l0 + seg*8;
    *(uint4*)&uth[off] = ph;
    *(uint4*)&utl[off] = pl;
  }
}

// ---------------------------------------------------------------------------
// K1: per-d setup, 256 threads/block (wave wv owns a 16-slice of s/r/m).
// Chains start via binary exponentiation; K[m] via 2-level LDS reduction.
// Emits pre-swizzled bf16 MFMA B-operand tables W2s/G2s/Th/Tl + P (f32).
// ---------------------------------------------------------------------------
__global__ __launch_bounds__(256) void k1_setup(
    const float* __restrict__ A_re, const float* __restrict__ A_im,
    const float* __restrict__ C_re, const float* __restrict__ C_im,
    const float* __restrict__ log_dt,
    ushort* __restrict__ W2s, ushort* __restrict__ G2s,
    ushort* __restrict__ Th2s, ushort* __restrict__ Tl2s,
    float2* __restrict__ P) {
  int d = blockIdx.x;
  int tid = threadIdx.x;
  int n = tid & 63, wv = tid >> 6;
  int idx = d * NN + n;

  __shared__ ushort Wl[8192], Gl[8192];
  __shared__ __align__(16) char smU[16640];   // Kp f32[64][65] | later Th/Tl
  ushort* Thl = (ushort*)smU;                 // 8 KB
  ushort* Tll = (ushort*)(smU + 8192);        // 8 KB
  float*  Kp  = (float*)smU;                  // 16.6 KB (dies at Kq)
  __shared__ float Kq[64][5];
  __shared__ float Kl[64];

  float dt  = expf(log_dt[d]);
  float dre = dt * A_re[idx], dim = dt * A_im[idx];
  float er  = expf(dre);
  float abr = er * cosf(dim), abi = er * sinf(dim);
  const float eps = 1e-8f;
  float nre = abr - 1.0f + eps, nim = abi;
  float qre = dre + eps,        qim = dim;
  float inv = 1.0f / (qre*qre + qim*qim);
  float bbr = dt * (nre*qre + nim*qim) * inv;
  float bbi = dt * (nim*qre - nre*qim) * inv;
  float2 a  = make_float2(abr, abi);
  float2 bb = make_float2(bbr, bbi);
  float2 cc = make_float2(C_re[idx], C_im[idx]);

  float2 a2  = cmul(a, a),   a4  = cmul(a2, a2);
  float2 a8  = cmul(a4, a4), a16 = cmul(a8, a8);
  float2 a32 = cmul(a16, a16), a48 = cmul(a32, a16);
  float2 pw_wv = make_float2(1.f, 0.f);
  for (int q = 0; q < wv; ++q) pw_wv = cmul(pw_wv, a16);

  if (wv == 0) P[idx] = cmul(a32, a32);

  // W slice: s in [wv*16, wv*16+15], descending; W[s] = bb*a^(63-s)
  {
    float2 sel = (wv == 0) ? a48 : (wv == 1) ? a32
               : (wv == 2) ? a16 : make_float2(1.f, 0.f);
    float2 w = cmul(bb, sel);
    for (int j = 15; j >= 0; --j) {
      int s = wv*16 + j;
      int ks = s >> 5, lk = (s >> 3) & 3, e = s & 7;
      {
        int n2 = 2*n; int nh = n2>>6, tq = (n2>>4)&3, lr = n2&15;
        Wl[(((nh*4+tq)*2+ks)*64 + lk*16+lr)*8 + e] = (ushort)f2b(w.x);
      }
      {
        int n2 = 2*n+1; int nh = n2>>6, tq = (n2>>4)&3, lr = n2&15;
        Wl[(((nh*4+tq)*2+ks)*64 + lk*16+lr)*8 + e] = (ushort)f2b(w.y);
      }
      w = cmul(w, a);
    }
  }
  // G slice: r in [wv*16, wv*16+15]; G[r] = cc*a^(r+1)
  {
    float2 g = cmul(cc, cmul(a, pw_wv));
    for (int j = 0; j < 16; ++j) {
      int r = wv*16 + j;
      int rh = r >> 5, tq = (r >> 4) & 1, lr = r & 15;
      {
        int n2 = 2*n; int ks = n2>>5, lk = (n2>>3)&3, e = n2&7;
        Gl[(((rh*2+tq)*4+ks)*64 + lk*16+lr)*8 + e] = (ushort)f2b(g.x);
      }
      {
        int n2 = 2*n+1; int ks = n2>>5, lk = (n2>>3)&3, e = n2&7;
        Gl[(((rh*2+tq)*4+ks)*64 + lk*16+lr)*8 + e] = (ushort)f2b(-g.y);
      }
      g = cmul(g, a);
    }
  }
  // K slice: Kp[m][n] = Re(cb * a^m), m in [wv*16, wv*16+15]
  {
    float2 cb = cmul(cc, bb);
    float2 t = cmul(cb, pw_wv);
    for (int j = 0; j < 16; ++j) {
      Kp[(wv*16 + j)*65 + n] = t.x;
      t = cmul(t, a);
    }
  }
  __syncthreads();
  {
    int m = tid >> 2, q = tid & 3;
    float s = 0.f;
    #pragma unroll
    for (int j = 0; j < 16; ++j) s += Kp[m*65 + q*16 + j];
    Kq[m][q] = s;
  }
  __syncthreads();
  if (tid < 64) Kl[tid] = Kq[tid][0] + Kq[tid][1] + Kq[tid][2] + Kq[tid][3];
  __syncthreads();                     // Kl ready; Kp dead -> Th/Tl reuse smU

  // Toeplitz frags (hi+lo): wave wv = (t*2+ks); 16 elems/thread
  {
    int tq = wv >> 1, ks = wv & 1;
    #pragma unroll
    for (int rh = 0; rh < 2; ++rh) {
      int r = rh*32 + tq*16 + (n & 15);
      #pragma unroll
      for (int e = 0; e < 8; ++e) {
        int s = ks*32 + (n >> 4)*8 + e;
        float val = (s <= r) ? Kl[r - s] : 0.f;
        unsigned hv = f2b(val);
        int o = rh*2048 + (wv*64 + n)*8 + e;
        Thl[o] = (ushort)hv;
        Tll[o] = (ushort)f2b(val - b2f(hv));
      }
    }
  }
  __syncthreads();
  {
    uint4* Wg  = (uint4*)(W2s  + (size_t)d * 8192);
    uint4* Gg  = (uint4*)(G2s  + (size_t)d * 8192);
    uint4* Thg = (uint4*)(Th2s + (size_t)d * 4096);
    uint4* Tlg = (uint4*)(Tl2s + (size_t)d * 4096);
    #pragma unroll
    for (int i = tid; i < 1024; i += 256) {
      Wg[i] = ((const uint4*)Wl)[i];
      Gg[i] = ((const uint4*)Gl)[i];
    }
    #pragma unroll
    for (int i = tid; i < 512; i += 256) {
      Thg[i] = ((const uint4*)Thl)[i];
      Tlg[i] = ((const uint4*)Tll)[i];
    }
  }
}

// ---------------------------------------------------------------------------
// K2 MFMA: Z-GEMM + split-precision Toeplitz conv + register-chain scan +
// cross-GEMM; writes full output column yt[b][d][:] in f32 (coalesced).
// Block (256 thr) per (b,d); XCD x hosts d in [x*64,x*64+64) (tables L2-hot).
// Scan: thread (n, wv) owns chunks c in [8wv, 8wv+8): serial in-register
// chain, cross-wave combine via Tbuf + p^8 (2 barriers total).
// ---------------------------------------------------------------------------
__global__ __launch_bounds__(256, 4) void k2_mfma(
    const ushort* __restrict__ uth, const ushort* __restrict__ utl,
    const ushort* __restrict__ W2s, const ushort* __restrict__ G2s,
    const ushort* __restrict__ Th2s, const ushort* __restrict__ Tl2s,
    const float2* __restrict__ P, float* __restrict__ yt) {
  int bid = blockIdx.x;
  int x = bid & 7;                     // XCD
  int d = x * 64 + ((bid >> 3) & 63);  // d-contiguous per XCD
  int b = bid >> 9;
  int tid = threadIdx.x;
  int l = tid & 63, wv = tid >> 6;
  int lr = l & 15, lk = l >> 4;
  int m0 = (wv & 1) * 16;              // c-half
  int half = wv >> 1;                  // n-half (B) / r-half (T,D)

  __shared__ __align__(16) char smem[8448 + 8192 + 17160];
  char*  u_hi = smem;                  // [33][128] bf16, rows c+1, swizzled
  char*  u_lo = smem + 4224;
  char*  Zs   = smem + 8448;           // [32][256] bf16 S_excl, swizzled
  float* Sf   = (float*)(smem + 16640);// [33][130] f32
  __shared__ float2 Tb[4][64];         // per-wave scan carries
  char*  ylds = smem;                  // alias (8704B), dead u tiles

  // --- stage u_hi/u_lo (pure coalesced 16B loads, no conversion VALU)
  {
    size_t off = ((size_t)(b * DD + d)) * LL + tid * 8;
    uint4 vh = *(const uint4*)&uth[off];
    uint4 vl = *(const uint4*)&utl[off];
    int row = (tid >> 3) + 1;
    int bo = row*128 + (((tid & 7) * 16) ^ ((row & 7) << 4));
    *(uint4*)(u_hi + bo) = vh;
    *(uint4*)(u_lo + bo) = vl;
  }
  __syncthreads();

  // --- B: Z-GEMM (u_hi) -> Sf rows c+1 (de-interleaved re/im cols)
  {
    const ushort* Wd = W2s + (size_t)d * 8192 + (size_t)half * 4096;
    f32x4 acc[4] = {{0,0,0,0},{0,0,0,0},{0,0,0,0},{0,0,0,0}};
    #pragma unroll
    for (int ks = 0; ks < 2; ++ks) {
      int arow = m0 + lr + 1;
      bf16x8 af = *(const bf16x8*)(u_hi + arow*128 +
                     ((ks*64 + lk*16) ^ ((arow & 7) << 4)));
      #pragma unroll
      for (int t = 0; t < 4; ++t) {
        bf16x8 bfr = *(const bf16x8*)(Wd + ((t*2 + ks)*64 + l)*8);
        acc[t] = __builtin_amdgcn_mfma_f32_16x16x32_bf16(af, bfr, acc[t], 0,0,0);
      }
    }
    #pragma unroll
    for (int t = 0; t < 4; ++t)
      #pragma unroll
      for (int j = 0; j < 4; ++j) {
        int c  = m0 + lk*4 + j;
        int n2 = half*64 + t*16 + lr;
        int col = (n2 >> 1) + (n2 & 1) * 64;
        Sf[(c + 1) * 130 + col] = acc[t][j];
      }
  }

  // --- T: split-precision local conv GEMM into acc2
  f32x4 acc2[2] = {{0,0,0,0},{0,0,0,0}};
  {
    const ushort* Tdh = Th2s + (size_t)d * 4096 + (size_t)half * 2048;
    const ushort* Tdl = Tl2s + (size_t)d * 4096 + (size_t)half * 2048;
    #pragma unroll
    for (int ks = 0; ks < 2; ++ks) {
      int arow = m0 + lr + 1;
      int aoff = (ks*64 + lk*16) ^ ((arow & 7) << 4);
      bf16x8 ah = *(const bf16x8*)(u_hi + arow*128 + aoff);
      bf16x8 al = *(const bf16x8*)(u_lo + arow*128 + aoff);
      #pragma unroll
      for (int t = 0; t < 2; ++t) {
        bf16x8 bh = *(const bf16x8*)(Tdh + ((t*2 + ks)*64 + l)*8);
        bf16x8 bl = *(const bf16x8*)(Tdl + ((t*2 + ks)*64 + l)*8);
        acc2[t] = __builtin_amdgcn_mfma_f32_16x16x32_bf16(ah, bh, acc2[t], 0,0,0);
        acc2[t] = __builtin_amdgcn_mfma_f32_16x16x32_bf16(al, bh, acc2[t], 0,0,0);
        acc2[t] = __builtin_amdgcn_mfma_f32_16x16x32_bf16(ah, bl, acc2[t], 0,0,0);
      }
    }
  }
  __syncthreads();                     // Sf visible; u tiles dead

  // --- register-chain scan: thread (n, wv) owns c in [8wv, 8wv+8)
  {
    int n = tid & 63;
    float2 p = P[(size_t)d * NN + n];  // a^64
    float2 z[8], loc[8];
    #pragma unroll
    for (int j = 0; j < 8; ++j) {
      int r = wv*8 + j + 1;
      z[j].x = Sf[r*130 + n];
      z[j].y = Sf[r*130 + 64 + n];
    }
    loc[0] = z[0];
    #pragma unroll
    for (int j = 1; j < 8; ++j)
      loc[j] = make_float2(fmaf(p.x, loc[j-1].x, fmaf(-p.y, loc[j-1].y, z[j].x)),
                           fmaf(p.x, loc[j-1].y, fmaf( p.y, loc[j-1].x, z[j].y)));
    Tb[wv][n] = loc[7];
    float2 p2 = cmul(p, p), p4 = cmul(p2, p2), p8 = cmul(p4, p4);
    __syncthreads();
    float2 Cw = make_float2(0.f, 0.f);
    for (int ww = 0; ww < wv; ++ww) {  // wave-uniform bound
      float2 t = Tb[ww][n];
      Cw = make_float2(fmaf(p8.x, Cw.x, fmaf(-p8.y, Cw.y, t.x)),
                       fmaf(p8.x, Cw.y, fmaf( p8.y, Cw.x, t.y)));
    }
    // S_excl[8wv] = Cw; S_excl[8wv+j] = loc[j-1] + p^j*Cw
    float2 q = Cw;
    *(unsigned*)(Zs + (wv*8)*256 + (4*n)) = f2b(q.x) | (f2b(q.y) << 16);
    #pragma unroll
    for (int j = 1; j < 8; ++j) {
      q = cmul(p, q);
      float2 v = make_float2(loc[j-1].x + q.x, loc[j-1].y + q.y);
      *(unsigned*)(Zs + (wv*8 + j)*256 + ((4*n) ^ (j << 4))) =
          f2b(v.x) | (f2b(v.y) << 16);
    }
  }
  __syncthreads();

  // --- D: cross GEMM accumulating into acc2
  {
    const ushort* Gd = G2s + (size_t)d * 8192 + (size_t)half * 4096;
    #pragma unroll
    for (int ks = 0; ks < 4; ++ks) {
      int arow = m0 + lr;
      bf16x8 af = *(const bf16x8*)(Zs + arow*256 +
                     ((ks*64 + lk*16) ^ ((arow & 7) << 4)));
      #pragma unroll
      for (int t = 0; t < 2; ++t) {
        bf16x8 bfr = *(const bf16x8*)(Gd + ((t*4 + ks)*64 + l)*8);
        acc2[t] = __builtin_amdgcn_mfma_f32_16x16x32_bf16(af, bfr, acc2[t], 0,0,0);
      }
    }
  }
  // --- out: acc2 -> ylds f32 [c][r] (stride 68: bank-clean) -> yt linear 8KB
  #pragma unroll
  for (int t = 0; t < 2; ++t)
    #pragma unroll
    for (int j = 0; j < 4; ++j) {
      int c = m0 + lk*4 + j;
      int r = half*32 + t*16 + lr;
      *(float*)(ylds + (c*68 + r)*4) = acc2[t][j];
    }
  __syncthreads();
  {
    int row = tid >> 3, col = (tid & 7) * 8;
    float4 o0 = *(const float4*)(ylds + (row*68 + col)*4);
    float4 o1 = *(const float4*)(ylds + (row*68 + col + 4)*4);
    float* dst = &yt[((size_t)(b * DD + d)) * LL + tid * 8];
    *(float4*)dst = o0;
    *(float4*)(dst + 4) = o1;
  }
}

// ---------------------------------------------------------------------------
// K4: transpose yt[b][d][l] f32 -> y[b][l][d] f32. Full 64x64 coverage.
// ---------------------------------------------------------------------------
__global__ __launch_bounds__(256) void k4_tr(
    const float* __restrict__ yt, float* __restrict__ y) {
  int bid = blockIdx.x;
  int dt8 = bid & 7, lt = (bid >> 3) & 31, b = bid >> 8;
  int l0 = lt * 64, d0 = dt8 * 64;
  int tid = threadIdx.x;
  __shared__ float tl[64][65];         // [d][l]
  #pragma unroll
  for (int it = 0; it < 2; ++it) {
    int row = it * 32 + (tid >> 3), seg = tid & 7;   // row = d
    const float* src = &yt[((size_t)(b*DD + d0 + row))*LL + l0 + seg*8];
    float4 v0 = *(const float4*)src;
    float4 v1 = *(const float4*)(src + 4);
    tl[row][seg*8+0]=v0.x; tl[row][seg*8+1]=v0.y;
    tl[row][seg*8+2]=v0.z; tl[row][seg*8+3]=v0.w;
    tl[row][seg*8+4]=v1.x; tl[row][seg*8+5]=v1.y;
    tl[row][seg*8+6]=v1.z; tl[row][seg*8+7]=v1.w;
  }
  __syncthreads();
  #pragma unroll
  for (int it = 0; it < 2; ++it) {
    int row = it * 32 + (tid >> 3), seg = tid & 7;   // row = l
    float o[8];
    #pragma unroll
    for (int j = 0; j < 8; ++j) o[j] = tl[seg*8 + j][row];
    float* dst = &y[((size_t)(b*LL + l0 + row))*DD + d0 + seg*8];
    *(float4*)dst = *(float4*)&o[0];
    *(float4*)(dst + 4) = *(float4*)&o[4];
  }
}

extern "C" void kernel_launch(void* const* d_in, const int* in_sizes, int n_in,
                              void* d_out, int out_size, void* d_ws, size_t ws_size,
                              hipStream_t stream) {
  const float* u      = (const float*)d_in[0];
  const float* A_re   = (const float*)d_in[1];
  const float* A_im   = (const float*)d_in[2];
  const float* C_re   = (const float*)d_in[3];
  const float* C_im   = (const float*)d_in[4];
  const float* log_dt = (const float*)d_in[5];
  float* y = (float*)d_out;

  // ws: yt f32 33.5MB | uth 16.8 | utl 16.8 | W2s 8.4 | G2s 8.4 | Th 4.2 | Tl 4.2 | P
  float*  yt  = (float*)d_ws;
  ushort* uth = (ushort*)(yt + (size_t)BB * DD * LL);
  ushort* utl = uth + (size_t)BB * DD * LL;
  ushort* W2s = utl + (size_t)BB * DD * LL;
  ushort* G2s = W2s + (size_t)DD * 8192;
  ushort* Th  = G2s + (size_t)DD * 8192;
  ushort* Tl  = Th  + (size_t)DD * 4096;
  float2* P   = (float2*)(Tl + (size_t)DD * 4096);

  k0_tr   <<<BB * 32 * 8, 256, 0, stream>>>(u, uth, utl);
  k1_setup<<<DD,          256, 0, stream>>>(A_re, A_im, C_re, C_im, log_dt,
                                            W2s, G2s, Th, Tl, P);
  k2_mfma <<<BB * DD,     256, 0, stream>>>(uth, utl, W2s, G2s, Th, Tl, P, yt);
  k4_tr   <<<BB * 32 * 8, 256, 0, stream>>>(yt, y);
}